// Round 5
// baseline (421.341 us; speedup 1.0000x reference)
//
#include <hip/hip_runtime.h>
#include <stdint.h>

#define D_IN1 34   // msg MLP in: 12+12+8+1+1
#define H1    32
#define D_IN2 28   // upd MLP in: 8+8+12
#define H2    16
#define CHN   12
#define CHE   8

__device__ __forceinline__ float clip100(float f) { return fminf(fmaxf(f, -100.f), 100.f); }

__device__ __forceinline__ float wave_sum64(float v) {
#pragma unroll
    for (int off = 32; off; off >>= 1) v += __shfl_xor(v, off);
    return v;
}

// ---- zero one contiguous region ----
__global__ void k_zero(int* __restrict__ p, int n_words) {
    int i = blockIdx.x * blockDim.x + threadIdx.x;
    if (i < n_words) p[i] = 0;
}

// ---- degrees via LDS histogram (wave-uniform fast path for sorted sources) ----
__global__ void k_degs(const int* __restrict__ src, const int* __restrict__ tgt,
                       int* __restrict__ outd, int* __restrict__ ind, int E, int N) {
    extern __shared__ int hist[];          // [2*N]
    int* ho = hist;
    int* hi = hist + N;
    for (int k = threadIdx.x; k < 2 * N; k += blockDim.x) hist[k] = 0;
    __syncthreads();
    for (int e = blockIdx.x * blockDim.x + threadIdx.x; e < E;
         e += gridDim.x * blockDim.x) {
        int s = src[e];
        int t = tgt[e];
        int s0 = __shfl(s, 0);
        unsigned long long act = __ballot(1);
        if (__all(s == s0)) {
            if ((threadIdx.x & 63) == 0) atomicAdd(&ho[s0], (int)__popcll(act));
        } else {
            atomicAdd(&ho[s], 1);
        }
        atomicAdd(&hi[t], 1);
    }
    __syncthreads();
    for (int k = threadIdx.x; k < N; k += blockDim.x) {
        int a = ho[k], b = hi[k];
        if (a) atomicAdd(&outd[k], a);
        if (b) atomicAdd(&ind[k], b);
    }
}

// ---- per-node layer-1 partials:
// SA[n][j] = sum_i W1[j][i]*node[i]      + W1[j][32]*outd[n]
// TB[n][j] = sum_i W1[j][12+i]*node[i]   + W1[j][33]*ind[n] + b1[j]
__launch_bounds__(256)
__global__ void k_pre(const float* __restrict__ nodes,
                      const int* __restrict__ outd, const int* __restrict__ ind,
                      const float* __restrict__ w1, const float* __restrict__ b1,
                      float* __restrict__ SA, float* __restrict__ TB,
                      int N, int total) {
    int i = blockIdx.x * blockDim.x + threadIdx.x;   // i = b*N + n
    if (i >= total) return;
    int n = i % N;

    float x[12];
    const float4* np = (const float4*)(nodes + (size_t)i * CHN);
    float4 n0 = np[0], n1 = np[1], n2 = np[2];
    x[0]=n0.x; x[1]=n0.y; x[2]=n0.z; x[3]=n0.w;
    x[4]=n1.x; x[5]=n1.y; x[6]=n1.z; x[7]=n1.w;
    x[8]=n2.x; x[9]=n2.y; x[10]=n2.z; x[11]=n2.w;
    float od  = (float)outd[n];
    float idg = (float)ind[n];

    float* sap = SA + (size_t)i * H1;
    float* tbp = TB + (size_t)i * H1;
#pragma unroll
    for (int h = 0; h < H1; ++h) {
        const float* wr = w1 + h * D_IN1;
        float a = wr[32] * od;
#pragma unroll
        for (int k = 0; k < 12; ++k) a = fmaf(wr[k], x[k], a);
        sap[h] = a;
        float c = fmaf(wr[33], idg, b1[h]);
#pragma unroll
        for (int k = 0; k < 12; ++k) c = fmaf(wr[12 + k], x[k], c);
        tbp[h] = c;
    }
}

// layer-1 for one edge: h[j] = relu(SA[s][j] + TB[t][j] + W1e[j]·x)
__device__ __forceinline__ void mlp1_one(const float* __restrict__ w1,
                                         const float4* sap, const float4* tbp,
                                         const float* x, float* h) {
#pragma unroll
    for (int q = 0; q < 8; ++q) {
        float4 a4 = sap[q], c4 = tbp[q];
        float hv[4] = { a4.x + c4.x, a4.y + c4.y, a4.z + c4.z, a4.w + c4.w };
#pragma unroll
        for (int r = 0; r < 4; ++r) {
            const float* wr = w1 + (4 * q + r) * D_IN1 + 24;
            float a = hv[r];
#pragma unroll
            for (int k = 0; k < 8; ++k) a = fmaf(wr[k], x[k], a);
            h[4 * q + r] = fmaxf(a, 0.f);
        }
    }
}

// layer-1 for an adjacent pair sharing the source row (SA loaded once)
__device__ __forceinline__ void mlp1_pair(const float* __restrict__ w1,
                                          const float4* sap,
                                          const float4* tbpA, const float4* tbpB,
                                          const float* xA, const float* xB,
                                          float* hA, float* hB) {
#pragma unroll
    for (int q = 0; q < 8; ++q) {
        float4 a4 = sap[q];
        float4 cA = tbpA[q], cB = tbpB[q];
        float vA4[4] = { a4.x + cA.x, a4.y + cA.y, a4.z + cA.z, a4.w + cA.w };
        float vB4[4] = { a4.x + cB.x, a4.y + cB.y, a4.z + cB.z, a4.w + cB.w };
#pragma unroll
        for (int r = 0; r < 4; ++r) {
            const float* wr = w1 + (4 * q + r) * D_IN1 + 24;
            float aa = vA4[r], ab = vB4[r];
#pragma unroll
            for (int k = 0; k < 8; ++k) {
                float w = wr[k];
                aa = fmaf(w, xA[k], aa);
                ab = fmaf(w, xB[k], ab);
            }
            hA[4 * q + r] = fmaxf(aa, 0.f);
            hB[4 * q + r] = fmaxf(ab, 0.f);
        }
    }
}

// ---- per-edge MLP + edge update; TWO adjacent edges per thread ----
// 2x independent chains/wave (latency overlap) + each weight s_load feeds 2 edges.
// NO min-waves hint: forcing it clamps VGPR (32) -> catastrophic scratch spill
// (rounds 1,3: FETCH+WRITE 2.03GB). Let the allocator float (~110-130 expected).
__launch_bounds__(512)
__global__ void k_edge(const float* __restrict__ edges,
                       const float* __restrict__ SA, const float* __restrict__ TB,
                       const float* __restrict__ w1, const float* __restrict__ w2,
                       const float* __restrict__ b2,
                       const int* __restrict__ src, const int* __restrict__ tgt,
                       float* __restrict__ agg_a, float* __restrict__ partials,
                       float* __restrict__ new_edges, int E, int N, int chunk, int nblk_alloc) {
    extern __shared__ float aggB[];        // [8][N], layout [c][t]
    int blk = blockIdx.x, b = blockIdx.y;
    int start = blk * chunk;
    if (start >= E) return;
    int end = min(E, start + chunk);

    for (int k = threadIdx.x; k < 8 * N; k += 512) aggB[k] = 0.f;
    __syncthreads();

    float* gab = agg_a + (size_t)b * N * 8;

    for (int base = start; base < end; base += 1024) {
        int eA = base + 2 * (int)threadIdx.x;
        int eB = eA + 1;
        bool vA = eA < end, vB = eB < end;

        int sA = 0, tA = 0, sB = 0, tB = 0;
        if (vA) { sA = src[eA]; tA = tgt[eA]; }
        if (vB) { sB = src[eB]; tB = tgt[eB]; }

        float xA[8], xB[8];
        if (vA) {
            const float4* ep = (const float4*)(edges + ((size_t)b * E + eA) * CHE);
            float4 p0 = ep[0], p1 = ep[1];
            xA[0]=p0.x; xA[1]=p0.y; xA[2]=p0.z; xA[3]=p0.w;
            xA[4]=p1.x; xA[5]=p1.y; xA[6]=p1.z; xA[7]=p1.w;
        }
        if (vB) {
            const float4* ep = (const float4*)(edges + ((size_t)b * E + eB) * CHE);
            float4 p0 = ep[0], p1 = ep[1];
            xB[0]=p0.x; xB[1]=p0.y; xB[2]=p0.z; xB[3]=p0.w;
            xB[4]=p1.x; xB[5]=p1.y; xB[6]=p1.z; xB[7]=p1.w;
        }

        const float4* sapA = (const float4*)(SA + ((size_t)b * N + sA) * H1);
        const float4* tbpA = (const float4*)(TB + ((size_t)b * N + tA) * H1);
        const float4* tbpB = (const float4*)(TB + ((size_t)b * N + tB) * H1);

        float hA[H1], hB[H1];
        if (__all(sA == sB)) {
            mlp1_pair(w1, sapA, tbpA, tbpB, xA, xB, hA, hB);
        } else {
            const float4* sapB = (const float4*)(SA + ((size_t)b * N + sB) * H1);
            mlp1_one(w1, sapA, tbpA, xA, hA);
            mlp1_one(w1, sapB, tbpB, xB, hB);
        }

        // layer 2, ordered to minimize live registers:
        // m_ab (o=16..23) first: consumes and frees xA/xB
#pragma unroll
        for (int o = 0; o < 8; ++o) {
            float aA = b2[16 + o], aB = aA;
#pragma unroll
            for (int j = 0; j < H1; ++j) {
                float w = w2[(16 + o) * H1 + j];
                aA = fmaf(w, hA[j], aA);
                aB = fmaf(w, hB[j], aB);
            }
            xA[o] = clip100(xA[o] + aA);
            xB[o] = clip100(xB[o] + aB);
        }
        if (vA) {
            float4* ow = (float4*)(new_edges + ((size_t)b * E + eA) * CHE);
            ow[0] = make_float4(xA[0], xA[1], xA[2], xA[3]);
            ow[1] = make_float4(xA[4], xA[5], xA[6], xA[7]);
        }
        if (vB) {
            float4* ow = (float4*)(new_edges + ((size_t)b * E + eB) * CHE);
            ow[0] = make_float4(xB[0], xB[1], xB[2], xB[3]);
            ow[1] = make_float4(xB[4], xB[5], xB[6], xB[7]);
        }

        // m_b (o=8..15): consumed immediately by LDS atomics
#pragma unroll
        for (int o = 0; o < 8; ++o) {
            float aA = b2[8 + o], aB = aA;
#pragma unroll
            for (int j = 0; j < H1; ++j) {
                float w = w2[(8 + o) * H1 + j];
                aA = fmaf(w, hA[j], aA);
                aB = fmaf(w, hB[j], aB);
            }
            if (vA) atomicAdd(&aggB[o * N + tA], aA);
            if (vB) atomicAdd(&aggB[o * N + tB], aB);
        }

        // m_a (o=0..7): kept for the agg_a reduction
        float maA[8], maB[8];
#pragma unroll
        for (int o = 0; o < 8; ++o) {
            float aA = b2[o], aB = aA;
#pragma unroll
            for (int j = 0; j < H1; ++j) {
                float w = w2[o * H1 + j];
                aA = fmaf(w, hA[j], aA);
                aB = fmaf(w, hB[j], aB);
            }
            maA[o] = aA; maB[o] = aB;
        }

        // agg_a: sources are monotone non-decreasing -> a wave's 128-edge window
        // has at most one run boundary almost always: 1-segment or 2-segment path.
        int s_lo = __shfl(sA, 0);
        int s_hi = __shfl(sB, 63);
        bool valid_all = __all(vA && vB);
        if (valid_all && __all((sA == s_lo || sA == s_hi) && (sB == s_lo || sB == s_hi))) {
            if (s_lo == s_hi) {
#pragma unroll
                for (int c = 0; c < 8; ++c) {
                    float vv = wave_sum64(maA[c] + maB[c]);
                    if ((threadIdx.x & 63) == 0) atomicAdd(&gab[(size_t)s_lo * 8 + c], vv);
                }
            } else {
#pragma unroll
                for (int c = 0; c < 8; ++c) {
                    float lo = (sA == s_lo ? maA[c] : 0.f) + (sB == s_lo ? maB[c] : 0.f);
                    float hi = (sA == s_hi ? maA[c] : 0.f) + (sB == s_hi ? maB[c] : 0.f);
                    lo = wave_sum64(lo);
                    hi = wave_sum64(hi);
                    if ((threadIdx.x & 63) == 0) {
                        atomicAdd(&gab[(size_t)s_lo * 8 + c], lo);
                        atomicAdd(&gab[(size_t)s_hi * 8 + c], hi);
                    }
                }
            }
        } else {
            if (vA) {
#pragma unroll
                for (int c = 0; c < 8; ++c) atomicAdd(&gab[(size_t)sA * 8 + c], maA[c]);
            }
            if (vB) {
#pragma unroll
                for (int c = 0; c < 8; ++c) atomicAdd(&gab[(size_t)sB * 8 + c], maB[c]);
            }
        }
    }

    __syncthreads();
    float* P = partials + ((size_t)b * nblk_alloc + blk) * 8 * N;
    for (int k = threadIdx.x; k < 8 * N; k += 512) P[k] = aggB[k];
}

// ---- sum per-block partials into agg_b [b][c][N]; p-dimension split P-way ----
__global__ void k_aggb(const float* __restrict__ partials, float* __restrict__ agg_b,
                       int nblk_used, int nblk_alloc, int span, int N, int totb) {
    int id = blockIdx.x * blockDim.x + threadIdx.x;
    if (id >= totb) return;
    int p0 = blockIdx.y * span;
    int p1 = min(nblk_used, p0 + span);
    if (p0 >= p1) return;
    int b = id / (8 * N);
    int r = id % (8 * N);
    float sum = 0.f;
    for (int p = p0; p < p1; ++p)
        sum += partials[((size_t)b * nblk_alloc + p) * 8 * N + r];
    atomicAdd(&agg_b[(size_t)b * 8 * N + r], sum);
}

// ---- per-node update MLP (agg_b layout [b][c][N]) ----
__launch_bounds__(256)
__global__ void k_upd(const float* __restrict__ nodes,
                      const float* __restrict__ agg_a, const float* __restrict__ agg_b,
                      const int* __restrict__ outd, const int* __restrict__ ind,
                      const float* __restrict__ u1, const float* __restrict__ ub1,
                      const float* __restrict__ u2, const float* __restrict__ ub2,
                      float* __restrict__ new_nodes, int N, int total) {
    int i = blockIdx.x * blockDim.x + threadIdx.x;
    if (i >= total) return;
    int b = i / N;
    int n = i % N;

    float rod = 1.f / fmaxf((float)outd[n], 1.f);
    float rdg = 1.f / fmaxf((float)ind[n], 1.f);

    float ux[D_IN2];
    const float4* ga = (const float4*)(agg_a + (size_t)i * 8);
    float4 a0 = ga[0], a1 = ga[1];
    ux[0] = a0.x * rod; ux[1] = a0.y * rod; ux[2] = a0.z * rod; ux[3] = a0.w * rod;
    ux[4] = a1.x * rod; ux[5] = a1.y * rod; ux[6] = a1.z * rod; ux[7] = a1.w * rod;
    const float* gb = agg_b + (size_t)b * 8 * N + n;
#pragma unroll
    for (int c = 0; c < 8; ++c) ux[8 + c] = gb[(size_t)c * N] * rdg;

    const float4* np4 = (const float4*)(nodes + (size_t)i * CHN);
    float4 n0 = np4[0], n1 = np4[1], n2 = np4[2];
    ux[16] = n0.x; ux[17] = n0.y; ux[18] = n0.z; ux[19] = n0.w;
    ux[20] = n1.x; ux[21] = n1.y; ux[22] = n1.z; ux[23] = n1.w;
    ux[24] = n2.x; ux[25] = n2.y; ux[26] = n2.z; ux[27] = n2.w;

    float hb[H2];
#pragma unroll
    for (int h = 0; h < H2; ++h) {
        float a = ub1[h];
#pragma unroll
        for (int k = 0; k < D_IN2; ++k) a = fmaf(u1[h * D_IN2 + k], ux[k], a);
        hb[h] = fmaxf(a, 0.f);
    }
#pragma unroll
    for (int o = 0; o < 8; ++o) {
        float a = ub2[o];
#pragma unroll
        for (int k = 0; k < H2; ++k) a = fmaf(u2[o * H2 + k], hb[k], a);
        ux[16 + o] = clip100(ux[16 + o] + a);
    }
    float4* onp = (float4*)(new_nodes + (size_t)i * CHN);
    onp[0] = make_float4(ux[16], ux[17], ux[18], ux[19]);
    onp[1] = make_float4(ux[20], ux[21], ux[22], ux[23]);
    onp[2] = n2;   // const channels 8..11 pass through
}

extern "C" void kernel_launch(void* const* d_in, const int* in_sizes, int n_in,
                              void* d_out, int out_size, void* d_ws, size_t ws_size,
                              hipStream_t stream) {
    const float* nodes = (const float*)d_in[0];
    const float* edges = (const float*)d_in[1];
    const float* mw1   = (const float*)d_in[2];
    const float* mb1   = (const float*)d_in[3];
    const float* mw2   = (const float*)d_in[4];
    const float* mb2   = (const float*)d_in[5];
    const float* uw1   = (const float*)d_in[6];
    const float* ubb1  = (const float*)d_in[7];
    const float* uw2   = (const float*)d_in[8];
    const float* ubb2  = (const float*)d_in[9];
    const int* src     = (const int*)d_in[10];
    const int* tgt     = (const int*)d_in[11];

    int E = in_sizes[10];
    int B = in_sizes[1] / (E * 8);
    int N = in_sizes[0] / (B * 12);

    // workspace: [outd | ind | pad | agg_a(B*8N) | agg_b(B*8N) | SA(B*N*32) | TB(B*N*32) | pad | partials]
    size_t off = 0;
    int* outd = (int*)((char*)d_ws + off);       off += (size_t)N * 4;
    int* ind  = (int*)((char*)d_ws + off);       off += (size_t)N * 4;
    off = (off + 63) & ~(size_t)63;
    float* agg_a = (float*)((char*)d_ws + off);  off += (size_t)B * N * 8 * 4;
    float* agg_b = (float*)((char*)d_ws + off);  off += (size_t)B * N * 8 * 4;
    size_t zbytes = off;                         // zero everything up to here
    float* SA = (float*)((char*)d_ws + off);     off += (size_t)B * N * H1 * 4;
    float* TB = (float*)((char*)d_ws + off);     off += (size_t)B * N * H1 * 4;
    off = (off + 63) & ~(size_t)63;
    float* partials = (float*)((char*)d_ws + off);

    // adaptive partial count: one [8][N] f32 slab per (batch, block)
    size_t per_blk = (size_t)B * 8 * N * sizeof(float);
    size_t avail = (ws_size > off) ? (ws_size - off) : 0;
    int nblk = (int)(avail / per_blk);
    if (nblk > 512) nblk = 512;
    if (nblk < 8)   nblk = 8;

    int zwords = (int)(zbytes / 4);
    k_zero<<<(zwords + 255) / 256, 256, 0, stream>>>((int*)d_ws, zwords);

    k_degs<<<256, 256, 2 * N * sizeof(int), stream>>>(src, tgt, outd, ind, E, N);

    int totn = B * N;
    k_pre<<<(totn + 255) / 256, 256, 0, stream>>>(nodes, outd, ind, mw1, mb1,
                                                  SA, TB, N, totn);

    float* out_nodes = (float*)d_out;
    float* out_edges = out_nodes + (size_t)B * N * 12;

    int chunk = (E + nblk - 1) / nblk;
    chunk = (chunk + 1023) & ~1023;             // dense 1024-wide (2-edge) iterations
    int nblk_used = (E + chunk - 1) / chunk;

    dim3 ge(nblk_used, B);
    k_edge<<<ge, 512, 8 * N * sizeof(float), stream>>>(
        edges, SA, TB, mw1, mw2, mb2, src, tgt,
        agg_a, partials, out_edges, E, N, chunk, nblk);

    int totb = B * 8 * N;
    const int P = 16;
    int span = (nblk_used + P - 1) / P;
    dim3 ga((totb + 255) / 256, P);
    k_aggb<<<ga, 256, 0, stream>>>(partials, agg_b, nblk_used, nblk, span, N, totb);

    k_upd<<<(totn + 255) / 256, 256, 0, stream>>>(nodes, agg_a, agg_b, outd, ind,
                                                  uw1, ubb1, uw2, ubb2,
                                                  out_nodes, N, totn);
}

// Round 6
// 380.002 us; speedup vs baseline: 1.1088x; 1.1088x over previous
//
#include <hip/hip_runtime.h>
#include <stdint.h>

#define D_IN1 34   // msg MLP in: 12+12+8+1+1
#define H1    32
#define D_IN2 28   // upd MLP in: 8+8+12
#define H2    16
#define CHN   12
#define CHE   8

__device__ __forceinline__ float clip100(float f) { return fminf(fmaxf(f, -100.f), 100.f); }

// ---- zero one contiguous region ----
__global__ void k_zero(int* __restrict__ p, int n_words) {
    int i = blockIdx.x * blockDim.x + threadIdx.x;
    if (i < n_words) p[i] = 0;
}

// ---- degrees via LDS histogram (wave-uniform fast path for sorted sources) ----
__global__ void k_degs(const int* __restrict__ src, const int* __restrict__ tgt,
                       int* __restrict__ outd, int* __restrict__ ind, int E, int N) {
    extern __shared__ int hist[];          // [2*N]
    int* ho = hist;
    int* hi = hist + N;
    for (int k = threadIdx.x; k < 2 * N; k += blockDim.x) hist[k] = 0;
    __syncthreads();
    for (int e = blockIdx.x * blockDim.x + threadIdx.x; e < E;
         e += gridDim.x * blockDim.x) {
        int s = src[e];
        int t = tgt[e];
        int s0 = __shfl(s, 0);
        unsigned long long act = __ballot(1);
        if (__all(s == s0)) {
            if ((threadIdx.x & 63) == 0) atomicAdd(&ho[s0], (int)__popcll(act));
        } else {
            atomicAdd(&ho[s], 1);
        }
        atomicAdd(&hi[t], 1);
    }
    __syncthreads();
    for (int k = threadIdx.x; k < N; k += blockDim.x) {
        int a = ho[k], b = hi[k];
        if (a) atomicAdd(&outd[k], a);
        if (b) atomicAdd(&ind[k], b);
    }
}

// ---- per-node layer-1 partials, written COLUMN-BLOCK TRANSPOSED:
// SAq[(b*8+q)*Npad + n] = float4(sa[4q..4q+3])   (same for TBq)
// sa[j] = sum_i W1[j][i]*node[i]    + W1[j][32]*outd[n]
// tb[j] = sum_i W1[j][12+i]*node[i] + W1[j][33]*ind[n] + b1[j]
// Rationale: k_edge's lanes read node-indexed rows with CONSECUTIVE t ->
// [q][node] layout makes each float4 load coalesce (16 lines vs 64).
__launch_bounds__(256)
__global__ void k_pre(const float* __restrict__ nodes,
                      const int* __restrict__ outd, const int* __restrict__ ind,
                      const float* __restrict__ w1, const float* __restrict__ b1,
                      float4* __restrict__ SAq, float4* __restrict__ TBq,
                      int N, int Npad, int total) {
    int i = blockIdx.x * blockDim.x + threadIdx.x;   // i = b*N + n
    if (i >= total) return;
    int n = i % N;
    int b = i / N;

    float x[12];
    const float4* np = (const float4*)(nodes + (size_t)i * CHN);
    float4 n0 = np[0], n1 = np[1], n2 = np[2];
    x[0]=n0.x; x[1]=n0.y; x[2]=n0.z; x[3]=n0.w;
    x[4]=n1.x; x[5]=n1.y; x[6]=n1.z; x[7]=n1.w;
    x[8]=n2.x; x[9]=n2.y; x[10]=n2.z; x[11]=n2.w;
    float od  = (float)outd[n];
    float idg = (float)ind[n];

    float sa[H1], tb[H1];
#pragma unroll
    for (int h = 0; h < H1; ++h) {
        const float* wr = w1 + h * D_IN1;
        float a = wr[32] * od;
#pragma unroll
        for (int k = 0; k < 12; ++k) a = fmaf(wr[k], x[k], a);
        sa[h] = a;
        float c = fmaf(wr[33], idg, b1[h]);
#pragma unroll
        for (int k = 0; k < 12; ++k) c = fmaf(wr[12 + k], x[k], c);
        tb[h] = c;
    }
#pragma unroll
    for (int q = 0; q < 8; ++q) {
        size_t idx = (size_t)(b * 8 + q) * Npad + n;
        SAq[idx] = make_float4(sa[4*q], sa[4*q+1], sa[4*q+2], sa[4*q+3]);
        TBq[idx] = make_float4(tb[4*q], tb[4*q+1], tb[4*q+2], tb[4*q+3]);
    }
}

// ---- per-edge MLP + edge update; agg_b into LDS [8][N] partial per block ----
// 512 threads, 1 edge/thread, LDS 35.4KB. NO min-waves hint: forcing it clamps
// VGPR (32) -> catastrophic scratch spill (rounds 1,3: FETCH+WRITE 2.03GB).
__launch_bounds__(512)
__global__ void k_edge(const float* __restrict__ edges,
                       const float4* __restrict__ SAq, const float4* __restrict__ TBq,
                       const float* __restrict__ w1, const float* __restrict__ w2,
                       const float* __restrict__ b2,
                       const int* __restrict__ src, const int* __restrict__ tgt,
                       float* __restrict__ agg_a, float* __restrict__ partials,
                       float* __restrict__ new_edges, int E, int N, int Npad,
                       int chunk, int nblk_alloc) {
    extern __shared__ float aggB[];        // [8][N], layout [c][t]
    int blk = blockIdx.x, b = blockIdx.y;
    int start = blk * chunk;
    if (start >= E) return;
    int end = min(E, start + chunk);

    for (int k = threadIdx.x; k < 8 * N; k += 512) aggB[k] = 0.f;
    __syncthreads();

    for (int base = start; base < end; base += 512) {
        int e = base + threadIdx.x;
        bool v = e < end;

        int s = 0, t = 0;
        float ma[8];

        if (v) { s = src[e]; t = tgt[e]; }

        float x[8];
        if (v) {
            const float4* ep = (const float4*)(edges + ((size_t)b * E + e) * CHE);
            float4 p0 = ep[0], p1 = ep[1];
            x[0]=p0.x; x[1]=p0.y; x[2]=p0.z; x[3]=p0.w;
            x[4]=p1.x; x[5]=p1.y; x[6]=p1.z; x[7]=p1.w;
        }

        // coalesced gathers: lanes' t are consecutive -> 16B-stride addresses
        float4 sa4[8], tb4[8];
#pragma unroll
        for (int q = 0; q < 8; ++q) {
            size_t bq = (size_t)(b * 8 + q) * Npad;
            sa4[q] = SAq[bq + s];
            tb4[q] = TBq[bq + t];
        }

        // layer 1: h[j] = relu(sa[j] + tb[j] + W1e[j]·x)
        float h[H1];
#pragma unroll
        for (int q = 0; q < 8; ++q) {
            const float* sp = (const float*)&sa4[q];
            const float* tp = (const float*)&tb4[q];
#pragma unroll
            for (int r = 0; r < 4; ++r) {
                const float* wr = w1 + (4 * q + r) * D_IN1 + 24;
                float a = sp[r] + tp[r];
#pragma unroll
                for (int k = 0; k < 8; ++k) a = fmaf(wr[k], x[k], a);
                h[4 * q + r] = fmaxf(a, 0.f);
            }
        }

        if (v) {
            // layer 2: m_ab (o=16..23) first -> consumes/frees x, writes edges
#pragma unroll
            for (int o = 0; o < 8; ++o) {
                float a = b2[16 + o];
#pragma unroll
                for (int j = 0; j < H1; ++j) a = fmaf(w2[(16 + o) * H1 + j], h[j], a);
                x[o] = clip100(x[o] + a);
            }
            float4* ow = (float4*)(new_edges + ((size_t)b * E + e) * CHE);
            ow[0] = make_float4(x[0], x[1], x[2], x[3]);
            ow[1] = make_float4(x[4], x[5], x[6], x[7]);

            // m_b (o=8..15): straight into LDS atomics
#pragma unroll
            for (int o = 0; o < 8; ++o) {
                float a = b2[8 + o];
#pragma unroll
                for (int j = 0; j < H1; ++j) a = fmaf(w2[(8 + o) * H1 + j], h[j], a);
                atomicAdd(&aggB[o * N + t], a);
            }

            // m_a (o=0..7): kept for the agg_a reduction
#pragma unroll
            for (int o = 0; o < 8; ++o) {
                float a = b2[o];
#pragma unroll
                for (int j = 0; j < H1; ++j) a = fmaf(w2[o * H1 + j], h[j], a);
                ma[o] = a;
            }
        }

        // agg_a: sources in long runs -> usually wave-uniform; butterfly + 1 atomic/ch
        int s0 = __shfl(s, 0);
        bool fast = __all(v && s == s0);
        if (fast) {
            float* ga = agg_a + ((size_t)b * N + s0) * 8;
#pragma unroll
            for (int c = 0; c < 8; ++c) {
                float vv = ma[c];
#pragma unroll
                for (int off = 32; off; off >>= 1) vv += __shfl_xor(vv, off);
                if ((threadIdx.x & 63) == 0) atomicAdd(&ga[c], vv);
            }
        } else if (v) {
            float* ga = agg_a + ((size_t)b * N + s) * 8;
#pragma unroll
            for (int c = 0; c < 8; ++c) atomicAdd(&ga[c], ma[c]);
        }
    }

    __syncthreads();
    float* P = partials + ((size_t)b * nblk_alloc + blk) * 8 * N;
    for (int k = threadIdx.x; k < 8 * N; k += 512) P[k] = aggB[k];
}

// ---- sum per-block partials into agg_b [b][c][N]; p-dimension split P-way ----
__global__ void k_aggb(const float* __restrict__ partials, float* __restrict__ agg_b,
                       int nblk_used, int nblk_alloc, int span, int N, int totb) {
    int id = blockIdx.x * blockDim.x + threadIdx.x;
    if (id >= totb) return;
    int p0 = blockIdx.y * span;
    int p1 = min(nblk_used, p0 + span);
    if (p0 >= p1) return;
    int b = id / (8 * N);
    int r = id % (8 * N);
    float sum = 0.f;
    for (int p = p0; p < p1; ++p)
        sum += partials[((size_t)b * nblk_alloc + p) * 8 * N + r];
    atomicAdd(&agg_b[(size_t)b * 8 * N + r], sum);
}

// ---- per-node update MLP (agg_b layout [b][c][N]) ----
__launch_bounds__(256)
__global__ void k_upd(const float* __restrict__ nodes,
                      const float* __restrict__ agg_a, const float* __restrict__ agg_b,
                      const int* __restrict__ outd, const int* __restrict__ ind,
                      const float* __restrict__ u1, const float* __restrict__ ub1,
                      const float* __restrict__ u2, const float* __restrict__ ub2,
                      float* __restrict__ new_nodes, int N, int total) {
    int i = blockIdx.x * blockDim.x + threadIdx.x;
    if (i >= total) return;
    int b = i / N;
    int n = i % N;

    float rod = 1.f / fmaxf((float)outd[n], 1.f);
    float rdg = 1.f / fmaxf((float)ind[n], 1.f);

    float ux[D_IN2];
    const float4* ga = (const float4*)(agg_a + (size_t)i * 8);
    float4 a0 = ga[0], a1 = ga[1];
    ux[0] = a0.x * rod; ux[1] = a0.y * rod; ux[2] = a0.z * rod; ux[3] = a0.w * rod;
    ux[4] = a1.x * rod; ux[5] = a1.y * rod; ux[6] = a1.z * rod; ux[7] = a1.w * rod;
    const float* gb = agg_b + (size_t)b * 8 * N + n;
#pragma unroll
    for (int c = 0; c < 8; ++c) ux[8 + c] = gb[(size_t)c * N] * rdg;

    const float4* np4 = (const float4*)(nodes + (size_t)i * CHN);
    float4 n0 = np4[0], n1 = np4[1], n2 = np4[2];
    ux[16] = n0.x; ux[17] = n0.y; ux[18] = n0.z; ux[19] = n0.w;
    ux[20] = n1.x; ux[21] = n1.y; ux[22] = n1.z; ux[23] = n1.w;
    ux[24] = n2.x; ux[25] = n2.y; ux[26] = n2.z; ux[27] = n2.w;

    float hb[H2];
#pragma unroll
    for (int h = 0; h < H2; ++h) {
        float a = ub1[h];
#pragma unroll
        for (int k = 0; k < D_IN2; ++k) a = fmaf(u1[h * D_IN2 + k], ux[k], a);
        hb[h] = fmaxf(a, 0.f);
    }
#pragma unroll
    for (int o = 0; o < 8; ++o) {
        float a = ub2[o];
#pragma unroll
        for (int k = 0; k < H2; ++k) a = fmaf(u2[o * H2 + k], hb[k], a);
        ux[16 + o] = clip100(ux[16 + o] + a);
    }
    float4* onp = (float4*)(new_nodes + (size_t)i * CHN);
    onp[0] = make_float4(ux[16], ux[17], ux[18], ux[19]);
    onp[1] = make_float4(ux[20], ux[21], ux[22], ux[23]);
    onp[2] = n2;   // const channels 8..11 pass through
}

extern "C" void kernel_launch(void* const* d_in, const int* in_sizes, int n_in,
                              void* d_out, int out_size, void* d_ws, size_t ws_size,
                              hipStream_t stream) {
    const float* nodes = (const float*)d_in[0];
    const float* edges = (const float*)d_in[1];
    const float* mw1   = (const float*)d_in[2];
    const float* mb1   = (const float*)d_in[3];
    const float* mw2   = (const float*)d_in[4];
    const float* mb2   = (const float*)d_in[5];
    const float* uw1   = (const float*)d_in[6];
    const float* ubb1  = (const float*)d_in[7];
    const float* uw2   = (const float*)d_in[8];
    const float* ubb2  = (const float*)d_in[9];
    const int* src     = (const int*)d_in[10];
    const int* tgt     = (const int*)d_in[11];

    int E = in_sizes[10];
    int B = in_sizes[1] / (E * 8);
    int N = in_sizes[0] / (B * 12);
    int Npad = (N + 63) & ~63;

    // workspace: [outd | ind | pad | agg_a(B*8N) | agg_b(B*8N) |
    //             SAq(B*8*Npad f4) | TBq(B*8*Npad f4) | pad | partials]
    size_t off = 0;
    int* outd = (int*)((char*)d_ws + off);       off += (size_t)N * 4;
    int* ind  = (int*)((char*)d_ws + off);       off += (size_t)N * 4;
    off = (off + 63) & ~(size_t)63;
    float* agg_a = (float*)((char*)d_ws + off);  off += (size_t)B * N * 8 * 4;
    float* agg_b = (float*)((char*)d_ws + off);  off += (size_t)B * N * 8 * 4;
    size_t zbytes = off;                         // zero everything up to here
    off = (off + 63) & ~(size_t)63;
    float4* SAq = (float4*)((char*)d_ws + off);  off += (size_t)B * 8 * Npad * 16;
    float4* TBq = (float4*)((char*)d_ws + off);  off += (size_t)B * 8 * Npad * 16;
    off = (off + 63) & ~(size_t)63;
    float* partials = (float*)((char*)d_ws + off);

    // adaptive partial count: one [8][N] f32 slab per (batch, block)
    size_t per_blk = (size_t)B * 8 * N * sizeof(float);
    size_t avail = (ws_size > off) ? (ws_size - off) : 0;
    int nblk = (int)(avail / per_blk);
    if (nblk > 512) nblk = 512;
    if (nblk < 8)   nblk = 8;

    int zwords = (int)(zbytes / 4);
    k_zero<<<(zwords + 255) / 256, 256, 0, stream>>>((int*)d_ws, zwords);

    k_degs<<<256, 256, 2 * N * sizeof(int), stream>>>(src, tgt, outd, ind, E, N);

    int totn = B * N;
    k_pre<<<(totn + 255) / 256, 256, 0, stream>>>(nodes, outd, ind, mw1, mb1,
                                                  SAq, TBq, N, Npad, totn);

    float* out_nodes = (float*)d_out;
    float* out_edges = out_nodes + (size_t)B * N * 12;

    int chunk = (E + nblk - 1) / nblk;
    chunk = (chunk + 511) & ~511;               // dense 512-wide iterations
    int nblk_used = (E + chunk - 1) / chunk;

    dim3 ge(nblk_used, B);
    k_edge<<<ge, 512, 8 * N * sizeof(float), stream>>>(
        edges, SAq, TBq, mw1, mw2, mb2, src, tgt,
        agg_a, partials, out_edges, E, N, Npad, chunk, nblk);

    int totb = B * 8 * N;
    const int P = 16;
    int span = (nblk_used + P - 1) / P;
    dim3 ga((totb + 255) / 256, P);
    k_aggb<<<ga, 256, 0, stream>>>(partials, agg_b, nblk_used, nblk, span, N, totb);

    k_upd<<<(totn + 255) / 256, 256, 0, stream>>>(nodes, agg_a, agg_b, outd, ind,
                                                  uw1, ubb1, uw2, ubb2,
                                                  out_nodes, N, totn);
}